// Round 3
// baseline (144.840 us; speedup 1.0000x reference)
//
#include <hip/hip_runtime.h>
#include <hip/hip_fp16.h>

// MyEncoder: B=8, S=4096, E=128, D=24, fp32 in/out.
// out = softmax((xWq+bq)(xWk+bk)^T / sqrt(128)) (xWv+bv) Wo + bo
// bf16-MFMA pipeline: prep -> proj (QKV GEMM) -> attn (flash partials,
// K-split, transposed scores, in-register P, full-K PV, MFMA-computed l)
// -> combine (sum fp16 partials + wO epilogue).
// Softmax without max-subtraction (scores tiny, shift-invariant) => K-split
// partials purely additive. exp2 with log2(e) folded into Q scale.
//
// R1: attn LDS-free, K/V streamed from L2 in MFMA layout -> latency-bound.
// R2: runtime-branch prefetch + rotate -> compiler sank the loads
//     (VGPR=40 proves it), vmcnt placed at the rotate => zero overlap.
// R3: nsp fixed at 8 COMPILE-TIME -> kchunk=512, 16 iterations, FULL
//     unroll. Prefetch guard folds to constants (no branch), rotate
//     copies become SSA renames, compiler hoists loads with counted
//     vmcnt. launch_bounds(256,6): VGPR cap 84 = 2-3 iters of loads in
//     flight, 24 waves/CU.

#define B_ 8
#define S_ 4096
#define E_ 128
#define D_ 24
#define N_ (B_ * S_)               // 32768 rows
#define SCALE 0.08838834764831845f // 1/sqrt(128)
#define LOG2E 1.4426950408889634f

#define NSP 8                      // K-splits (compile-time)
#define KCHUNK (S_ / NSP)          // 512 keys per split

#define HS_STRIDE 40               // H_s row stride in combine
#define XS_STRIDE 136              // x_s row stride (bf16) in proj
#define OS_STRIDE 84               // out_s row stride (fp32) in proj

typedef __attribute__((ext_vector_type(8))) short bfrag;   // 8 bf16 = 4 VGPR
typedef __attribute__((ext_vector_type(4))) float ffrag;   // 4 fp32 acc

__device__ inline unsigned short f2bf(float f) {           // RNE fp32->bf16
    unsigned int x = __builtin_bit_cast(unsigned int, f);
    return (unsigned short)((x + 0x7fffu + ((x >> 16) & 1u)) >> 16);
}
// round-half-up bf16 pair pack: 2 int-adds + v_perm (validated on HW)
__device__ inline unsigned int pack2h(float a, float b) {
    unsigned int ua = __builtin_bit_cast(unsigned int, a) + 0x8000u;
    unsigned int ub = __builtin_bit_cast(unsigned int, b) + 0x8000u;
    return __builtin_amdgcn_perm(ub, ua, 0x07060302);      // [b.hi16 | a.hi16]
}
// fp16 pair pack, RTZ, single v_cvt_pkrtz_f16_f32
__device__ inline unsigned int packh16(float a, float b) {
    return __builtin_bit_cast(unsigned int, __builtin_amdgcn_cvt_pkrtz(a, b));
}

// ---------------- Kernel 0: weight prep (8 blocks) ----------------
// Wf  [kt=4][nt=5][lane=64][j=8]: W[k][n], k=kt*32+quad*8+j, n=nt*16+(lane&15)
//     W = [wQ*SCALE*LOG2E | wK | wV | 0pad] (128 x 80)
// wOf [nt=8][lane=64][j=8]: wO[k][e], k=quad*8+j (zero for k>=24)
// bqkv[80] fp32 = [bQ*SCALE*LOG2E | bK | bV | 0]
__global__ __launch_bounds__(256) void prep_kernel(
    const float* __restrict__ wQ, const float* __restrict__ bQ,
    const float* __restrict__ wK, const float* __restrict__ bK,
    const float* __restrict__ wV, const float* __restrict__ bV,
    const float* __restrict__ wO,
    unsigned short* __restrict__ Wf, unsigned short* __restrict__ wOf,
    float* __restrict__ bqkv)
{
    const int gtid   = blockIdx.x * 256 + threadIdx.x;
    const int stride = gridDim.x * 256;
    const float qs = SCALE * LOG2E;
    for (int idx = gtid; idx < 4 * 5 * 512; idx += stride) {
        const int j    = idx & 7;
        const int lane = (idx >> 3) & 63;
        const int nt   = (idx >> 9) % 5;
        const int kt   = idx / 2560;
        const int n = nt * 16 + (lane & 15);
        const int k = kt * 32 + ((lane >> 4) << 3) + j;
        float v = 0.0f;
        if (n < 24)      v = wQ[k * 24 + n] * qs;
        else if (n < 48) v = wK[k * 24 + (n - 24)];
        else if (n < 72) v = wV[k * 24 + (n - 48)];
        Wf[idx] = f2bf(v);
    }
    for (int idx = gtid; idx < 8 * 512; idx += stride) {
        const int j    = idx & 7;
        const int lane = (idx >> 3) & 63;
        const int nt   = idx >> 9;
        const int k = ((lane >> 4) << 3) + j;
        const int e = nt * 16 + (lane & 15);
        wOf[idx] = (k < 24) ? f2bf(wO[k * 128 + e]) : (unsigned short)0;
    }
    if (gtid < 80) {
        float v = 0.0f;
        if (gtid < 24)      v = bQ[gtid] * qs;
        else if (gtid < 48) v = bK[gtid - 24];
        else if (gtid < 72) v = bV[gtid - 48];
        bqkv[gtid] = v;
    }
}

// ---------------- Kernel 1: QKV projection (MFMA) ----------------
__global__ __launch_bounds__(256) void proj_kernel(
    const float* __restrict__ x, const unsigned short* __restrict__ Wf,
    const float* __restrict__ bqkv,
    unsigned short* __restrict__ Qbf, unsigned short* __restrict__ Kbf,
    unsigned short* __restrict__ Vt)
{
    __shared__ float smem[64 * OS_STRIDE];          // 21504 B, dual-purpose
    unsigned short* xs = (unsigned short*)smem;     // [64][XS_STRIDE]
    float* os = smem;                               // [64][OS_STRIDE]

    const int tid  = threadIdx.x;
    const int lane = tid & 63;
    const int w    = tid >> 6;
    const int col  = lane & 15;
    const int quad = lane >> 4;
    const int rb   = blockIdx.x * 64;

    #pragma unroll
    for (int i = 0; i < 8; ++i) {
        const int idx = i * 256 + tid;
        const int row = idx >> 5, c4 = idx & 31;
        const float4 xv = *(const float4*)(x + (size_t)(rb + row) * 128 + c4 * 4);
        uint2 h;
        h.x = pack2h(xv.x, xv.y);
        h.y = pack2h(xv.z, xv.w);
        *(uint2*)(&xs[row * XS_STRIDE + c4 * 4]) = h;
    }

    bfrag Wfr[20];
    #pragma unroll
    for (int f = 0; f < 20; ++f)
        Wfr[f] = *(const bfrag*)(Wf + (f * 64 + lane) * 8);

    __syncthreads();

    ffrag acc[5];
    #pragma unroll
    for (int nt = 0; nt < 5; ++nt) acc[nt] = (ffrag){0.f, 0.f, 0.f, 0.f};

    #pragma unroll
    for (int kt = 0; kt < 4; ++kt) {
        const bfrag Af = *(const bfrag*)(&xs[(w * 16 + col) * XS_STRIDE + kt * 32 + quad * 8]);
        #pragma unroll
        for (int nt = 0; nt < 5; ++nt)
            acc[nt] = __builtin_amdgcn_mfma_f32_16x16x32_bf16(Af, Wfr[kt * 5 + nt], acc[nt], 0, 0, 0);
    }

    __syncthreads();

    #pragma unroll
    for (int nt = 0; nt < 5; ++nt) {
        const float bb = bqkv[nt * 16 + col];
        #pragma unroll
        for (int r = 0; r < 4; ++r)
            os[(w * 16 + quad * 4 + r) * OS_STRIDE + nt * 16 + col] = acc[nt][r] + bb;
    }
    __syncthreads();

    // Q (tid<128) / K (tid>=128): row-major bf16, cols padded to 32
    {
        const int half  = tid & 1;
        const int row   = (tid >> 1) & 63;
        const int isK   = tid >> 7;
        const int cbase = isK * 24;
        unsigned int pk[8];
        #pragma unroll
        for (int g = 0; g < 8; ++g) {
            const int c0 = half * 16 + g * 2;
            const float f0 = (c0     < 24) ? os[row * OS_STRIDE + cbase + c0]     : 0.0f;
            const float f1 = (c0 + 1 < 24) ? os[row * OS_STRIDE + cbase + c0 + 1] : 0.0f;
            pk[g] = pack2h(f0, f1);
        }
        unsigned short* dst = (isK ? Kbf : Qbf) + (size_t)(rb + row) * 32 + half * 16;
        *(uint4*)(dst)     = make_uint4(pk[0], pk[1], pk[2], pk[3]);
        *(uint4*)(dst + 8) = make_uint4(pk[4], pk[5], pk[6], pk[7]);
    }

    // Vt: transposed [b][d][s], 32 d-rows per batch, 16B stores
    if (tid < 192) {
        const int d  = tid % 24;
        const int ch = tid / 24;
        unsigned int p[4];
        #pragma unroll
        for (int g = 0; g < 4; ++g) {
            const float f0 = os[(ch * 8 + g * 2 + 0) * OS_STRIDE + 48 + d];
            const float f1 = os[(ch * 8 + g * 2 + 1) * OS_STRIDE + 48 + d];
            p[g] = pack2h(f0, f1);
        }
        const int b = rb >> 12, s0 = rb & 4095;
        uint4* dst = (uint4*)(Vt + (((size_t)(b * 32 + d)) << 12) + s0 + ch * 8);
        *dst = make_uint4(p[0], p[1], p[2], p[3]);
    } else if (tid < 200) {
        // ones row d=24 (l via PV MFMA); rows 25..31 never read
        const int ch = tid - 192;
        const int b = rb >> 12, s0 = rb & 4095;
        uint4* dst = (uint4*)(Vt + (((size_t)(b * 32 + 24)) << 12) + s0 + ch * 8);
        *dst = make_uint4(0x3F803F80u, 0x3F803F80u, 0x3F803F80u, 0x3F803F80u);
    }
}

// ---------------- Kernel 2: flash attention partials ----------------
// Grid (N/128, NSP), 256 threads = 4 waves; each wave owns 32 q (2 frags).
// NO LDS, NO BARRIERS: K and V fragments loaded directly from global in
// MFMA layout (L2-resident), key-permutation folded into per-lane base
// keyE = ((col>>2)<<3)+(col&3). V row d=24 = 1.0 so the PV MFMA computes
// l in Ot1's d=24 element; d>24 lanes redirected to the ones row.
// R3: compile-time trip count (KCHUNK/32 = 16), FULL unroll, prefetch
// guard is a per-copy constant -> no branch, rotate copies are SSA
// renames -> compiler hoists loads with counted vmcnt.
__global__ __launch_bounds__(256, 6) void attn_kernel(
    const unsigned short* __restrict__ Qbf, const unsigned short* __restrict__ Kbf,
    const unsigned short* __restrict__ Vt,
    __half* __restrict__ Opart, float* __restrict__ lpart)
{
    const int tid    = threadIdx.x;
    const int lane   = tid & 63;
    const int w      = tid >> 6;                      // 0..3
    const int col    = lane & 15;
    const int quad   = lane >> 4;
    const int blk    = blockIdx.x;                    // 0..N/128-1
    const int split  = blockIdx.y;                    // 0..NSP-1
    const int b      = blk >> 5;                      // 32 blocks per batch
    const int qbase  = blk * 128 + w * 32;            // 32 q per wave

    // two Q fragments (B-operand: lane holds Q[q=col][k=quad*8+j])
    const bfrag Qf0 = *(const bfrag*)(Qbf + (size_t)(qbase + col) * 32 + quad * 8);
    const bfrag Qf1 = *(const bfrag*)(Qbf + (size_t)(qbase + 16 + col) * 32 + quad * 8);

    // K even-fragment per-lane base: key-in-32 = ((col>>2)<<3)+(col&3)
    const int keyE = ((col >> 2) << 3) + (col & 3);
    const unsigned short* Kp =
        Kbf + ((size_t)b * 4096 + (size_t)split * KCHUNK + keyE) * 32 + quad * 8;
    // V rows: Va0 d=col (0..15); Va1 d=16+col, d>24 -> ones row 24
    const int d1 = (16 + col <= 24) ? (16 + col) : 24;
    const unsigned short* Vp0 =
        Vt + ((size_t)(b * 32 + col)) * 4096 + (size_t)split * KCHUNK + quad * 8;
    const unsigned short* Vp1 =
        Vt + ((size_t)(b * 32 + d1)) * 4096 + (size_t)split * KCHUNK + quad * 8;

    ffrag O00 = {0.f,0.f,0.f,0.f};   // frag0: O^T d = quad*4+r     (0..15)
    ffrag O01 = {0.f,0.f,0.f,0.f};   // frag0: O^T d = 16+quad*4+r  (d=24 is l)
    ffrag O10 = {0.f,0.f,0.f,0.f};   // frag1
    ffrag O11 = {0.f,0.f,0.f,0.f};

    // prologue: iteration 0 loads
    bfrag cKfe = *(const bfrag*)(Kp);
    bfrag cKfo = *(const bfrag*)(Kp + 128);
    bfrag cVa0 = *(const bfrag*)(Vp0);
    bfrag cVa1 = *(const bfrag*)(Vp1);

    #pragma unroll
    for (int it = 0; it < KCHUNK; it += 32) {
        // next iteration's loads (guard folds to compile-time constant)
        bfrag nKfe, nKfo, nVa0, nVa1;
        if (it + 32 < KCHUNK) {
            const unsigned short* Kn  = Kp  + (size_t)(it / 32 + 1) * 1024;
            const unsigned short* Vn0 = Vp0 + (size_t)(it + 32);
            const unsigned short* Vn1 = Vp1 + (size_t)(it + 32);
            nKfe = *(const bfrag*)(Kn);
            nKfo = *(const bfrag*)(Kn + 128);
            nVa0 = *(const bfrag*)(Vn0);
            nVa1 = *(const bfrag*)(Vn1);
        }

        // ---- fragment 0 (q = qbase..qbase+15) ----
        {
            ffrag Se = {0.f,0.f,0.f,0.f}, So = {0.f,0.f,0.f,0.f};
            Se = __builtin_amdgcn_mfma_f32_16x16x32_bf16(cKfe, Qf0, Se, 0, 0, 0);
            So = __builtin_amdgcn_mfma_f32_16x16x32_bf16(cKfo, Qf0, So, 0, 0, 0);
            union { bfrag f; unsigned int u[4]; } P;
            P.u[0] = pack2h(__builtin_amdgcn_exp2f(Se[0]), __builtin_amdgcn_exp2f(Se[1]));
            P.u[1] = pack2h(__builtin_amdgcn_exp2f(Se[2]), __builtin_amdgcn_exp2f(Se[3]));
            P.u[2] = pack2h(__builtin_amdgcn_exp2f(So[0]), __builtin_amdgcn_exp2f(So[1]));
            P.u[3] = pack2h(__builtin_amdgcn_exp2f(So[2]), __builtin_amdgcn_exp2f(So[3]));
            O00 = __builtin_amdgcn_mfma_f32_16x16x32_bf16(cVa0, P.f, O00, 0, 0, 0);
            O01 = __builtin_amdgcn_mfma_f32_16x16x32_bf16(cVa1, P.f, O01, 0, 0, 0);
        }
        // ---- fragment 1 (q = qbase+16..qbase+31) ----
        {
            ffrag Se = {0.f,0.f,0.f,0.f}, So = {0.f,0.f,0.f,0.f};
            Se = __builtin_amdgcn_mfma_f32_16x16x32_bf16(cKfe, Qf1, Se, 0, 0, 0);
            So = __builtin_amdgcn_mfma_f32_16x16x32_bf16(cKfo, Qf1, So, 0, 0, 0);
            union { bfrag f; unsigned int u[4]; } P;
            P.u[0] = pack2h(__builtin_amdgcn_exp2f(Se[0]), __builtin_amdgcn_exp2f(Se[1]));
            P.u[1] = pack2h(__builtin_amdgcn_exp2f(Se[2]), __builtin_amdgcn_exp2f(Se[3]));
            P.u[2] = pack2h(__builtin_amdgcn_exp2f(So[0]), __builtin_amdgcn_exp2f(So[1]));
            P.u[3] = pack2h(__builtin_amdgcn_exp2f(So[2]), __builtin_amdgcn_exp2f(So[3]));
            O10 = __builtin_amdgcn_mfma_f32_16x16x32_bf16(cVa0, P.f, O10, 0, 0, 0);
            O11 = __builtin_amdgcn_mfma_f32_16x16x32_bf16(cVa1, P.f, O11, 0, 0, 0);
        }

        // rotate (pure renames after full unroll)
        cKfe = nKfe; cKfo = nKfo; cVa0 = nVa0; cVa1 = nVa1;
    }

    // store fp16 partials: O^T -> Opart[q][d]; l from Ot1 d=24 (quad 2, r=0)
    {
        const size_t base0 = ((size_t)split * N_ + qbase + col) * 32;
        uint2 s0;
        s0.x = packh16(O00[0], O00[1]);
        s0.y = packh16(O00[2], O00[3]);
        *(uint2*)(Opart + base0 + quad * 4) = s0;
        if (quad < 2) {
            uint2 s1;
            s1.x = packh16(O01[0], O01[1]);
            s1.y = packh16(O01[2], O01[3]);
            *(uint2*)(Opart + base0 + 16 + quad * 4) = s1;   // d 16..23
        }
        if (quad == 2)
            lpart[(size_t)split * N_ + qbase + col] = O01[0]; // d=24 = l

        const size_t base1 = base0 + 16 * 32;
        uint2 t0;
        t0.x = packh16(O10[0], O10[1]);
        t0.y = packh16(O10[2], O10[3]);
        *(uint2*)(Opart + base1 + quad * 4) = t0;
        if (quad < 2) {
            uint2 t1;
            t1.x = packh16(O11[0], O11[1]);
            t1.y = packh16(O11[2], O11[3]);
            *(uint2*)(Opart + base1 + 16 + quad * 4) = t1;
        }
        if (quad == 2)
            lpart[(size_t)split * N_ + qbase + 16 + col] = O11[0];
    }
}

// ---------------- Kernel 3: combine + output projection ----------------
__global__ __launch_bounds__(256) void combine_kernel(
    const __half* __restrict__ Opart, const float* __restrict__ lpart,
    const unsigned short* __restrict__ wOf, const float* __restrict__ bO,
    float* __restrict__ out)
{
    __shared__ unsigned short Hs[64 * HS_STRIDE];

    const int tid = threadIdx.x;
    const int qb  = blockIdx.x * 64;
    {
        const int ql = tid >> 2;
        const int c8 = (tid & 3) * 8;     // dim chunk 0,8,16,24
        const int q  = qb + ql;
        float a[8] = {0.f, 0.f, 0.f, 0.f, 0.f, 0.f, 0.f, 0.f};
        if (c8 < 24) {                    // chunk 24..31 never written -> zeros
            #pragma unroll
            for (int s = 0; s < NSP; ++s) {
                const __half2* p2 = (const __half2*)(Opart + ((size_t)s * N_ + q) * 32 + c8);
                #pragma unroll
                for (int j = 0; j < 4; ++j) {
                    const float2 f = __half22float2(p2[j]);
                    a[2 * j]     += f.x;
                    a[2 * j + 1] += f.y;
                }
            }
        }
        float ls = 0.f;
        #pragma unroll
        for (int s = 0; s < NSP; ++s) ls += lpart[(size_t)s * N_ + q];
        const float inv = 1.0f / ls;
        uint4 pk;
        pk.x = pack2h(a[0] * inv, a[1] * inv);
        pk.y = pack2h(a[2] * inv, a[3] * inv);
        pk.z = pack2h(a[4] * inv, a[5] * inv);
        pk.w = pack2h(a[6] * inv, a[7] * inv);
        *(uint4*)(&Hs[ql * HS_STRIDE + c8]) = pk;
    }
    __syncthreads();

    const int lane = tid & 63;
    const int w    = tid >> 6;
    const int col  = lane & 15;
    const int quad = lane >> 4;
    const bfrag Hf = *(const bfrag*)(&Hs[(w * 16 + col) * HS_STRIDE + quad * 8]);
    #pragma unroll
    for (int nt = 0; nt < 8; ++nt) {
        const bfrag Wo = *(const bfrag*)(wOf + (nt * 64 + lane) * 8);
        ffrag C = {0.f, 0.f, 0.f, 0.f};
        C = __builtin_amdgcn_mfma_f32_16x16x32_bf16(Hf, Wo, C, 0, 0, 0);
        const float bo = bO[nt * 16 + col];
        #pragma unroll
        for (int r = 0; r < 4; ++r)
            out[(size_t)(qb + w * 16 + quad * 4 + r) * 128 + nt * 16 + col] = C[r] + bo;
    }
}

extern "C" void kernel_launch(void* const* d_in, const int* in_sizes, int n_in,
                              void* d_out, int out_size, void* d_ws, size_t ws_size,
                              hipStream_t stream) {
    const float* x  = (const float*)d_in[0];
    const float* wQ = (const float*)d_in[1];
    const float* bQ = (const float*)d_in[2];
    const float* wK = (const float*)d_in[3];
    const float* bK = (const float*)d_in[4];
    const float* wV = (const float*)d_in[5];
    const float* bV = (const float*)d_in[6];
    const float* wO = (const float*)d_in[7];
    const float* bO = (const float*)d_in[8];
    float* out = (float*)d_out;

    unsigned short* ws16 = (unsigned short*)d_ws;
    unsigned short* Qbf = ws16;                                    // N*32 shorts
    unsigned short* Kbf = Qbf + (size_t)N_ * 32;                   // N*32
    unsigned short* Vt  = Kbf + (size_t)N_ * 32;                   // B*32*S
    unsigned short* Wf  = Vt + (size_t)B_ * 32 * S_;               // 10240
    unsigned short* wOf = Wf + 4 * 5 * 512;                        // 4096
    float* bqkv = (float*)(wOf + 8 * 512);                         // 80 fp32
    __half* Opart = (__half*)(bqkv + 80);                          // NSP*N*32 fp16
    float* lpart = (float*)(Opart + (size_t)NSP * N_ * 32);        // NSP*N fp32

    prep_kernel<<<8, 256, 0, stream>>>(wQ, bQ, wK, bK, wV, bV, wO, Wf, wOf, bqkv);
    proj_kernel<<<N_ / 64, 256, 0, stream>>>(x, Wf, bqkv, Qbf, Kbf, Vt);
    attn_kernel<<<dim3(N_ / 128, NSP), 256, 0, stream>>>(Qbf, Kbf, Vt, Opart, lpart);
    combine_kernel<<<N_ / 64, 256, 0, stream>>>(Opart, lpart, wOf, bO, out);
}

// Round 4
// 139.768 us; speedup vs baseline: 1.0363x; 1.0363x over previous
//
#include <hip/hip_runtime.h>
#include <hip/hip_fp16.h>

// MyEncoder: B=8, S=4096, E=128, D=24, fp32 in/out.
// out = softmax((xWq+bq)(xWk+bk)^T / sqrt(128)) (xWv+bv) Wo + bo
// bf16-MFMA pipeline: prep -> proj (QKV GEMM) -> attn (flash partials,
// K-split, transposed scores, in-register P, full-K PV, MFMA-computed l)
// -> combine (sum fp16 partials + wO epilogue).
// Softmax without max-subtraction (scores tiny, shift-invariant) => K-split
// partials purely additive. exp2 with log2(e) folded into Q scale.
//
// R1: attn LDS-free, K/V streamed from L2 in MFMA layout -> latency-bound.
// R2/R3: compiler-scheduled prefetch (branch+rotate, then full unroll)
//     -> hipcc sinks loads to uses both times (VGPR=40), zero overlap.
// R4: inline-asm pipeline. All attn loads are asm volatile
//     global_load_dwordx4 (compiler can't see/sink them, volatile order
//     is preserved), prefetch distance 2, counted s_waitcnt vmcnt(8/4/0)
//     + sched_barrier(0) after each wait (rule #18: MFMA must not hoist
//     above the wait). launch_bounds(256,4): ~100 VGPR, 16 waves/CU.

#define B_ 8
#define S_ 4096
#define E_ 128
#define D_ 24
#define N_ (B_ * S_)               // 32768 rows
#define SCALE 0.08838834764831845f // 1/sqrt(128)
#define LOG2E 1.4426950408889634f

#define NSP 8                      // K-splits (compile-time)
#define KCHUNK (S_ / NSP)          // 512 keys per split
#define NIT (KCHUNK / 32)          // 16 iterations of 32 keys

#define HS_STRIDE 40               // H_s row stride in combine
#define XS_STRIDE 136              // x_s row stride (bf16) in proj
#define OS_STRIDE 84               // out_s row stride (fp32) in proj

typedef __attribute__((ext_vector_type(8))) short bfrag;   // 8 bf16 = 4 VGPR
typedef __attribute__((ext_vector_type(4))) float ffrag;   // 4 fp32 acc
typedef __attribute__((ext_vector_type(4))) unsigned int u32x4;

__device__ inline unsigned short f2bf(float f) {           // RNE fp32->bf16
    unsigned int x = __builtin_bit_cast(unsigned int, f);
    return (unsigned short)((x + 0x7fffu + ((x >> 16) & 1u)) >> 16);
}
// round-half-up bf16 pair pack: 2 int-adds + v_perm (validated on HW)
__device__ inline unsigned int pack2h(float a, float b) {
    unsigned int ua = __builtin_bit_cast(unsigned int, a) + 0x8000u;
    unsigned int ub = __builtin_bit_cast(unsigned int, b) + 0x8000u;
    return __builtin_amdgcn_perm(ub, ua, 0x07060302);      // [b.hi16 | a.hi16]
}
// fp16 pair pack, RTZ, single v_cvt_pkrtz_f16_f32
__device__ inline unsigned int packh16(float a, float b) {
    return __builtin_bit_cast(unsigned int, __builtin_amdgcn_cvt_pkrtz(a, b));
}
// 16B global load the compiler cannot sink or auto-wait on.
// volatile asm statements preserve mutual program order -> issue order is
// exactly source order, so counted vmcnt(N) retires deterministic groups.
__device__ inline bfrag gload16(const unsigned short* p) {
    u32x4 d;
    asm volatile("global_load_dwordx4 %0, %1, off" : "=v"(d) : "v"(p));
    return __builtin_bit_cast(bfrag, d);
}

// ---------------- Kernel 0: weight prep (8 blocks) ----------------
// Wf  [kt=4][nt=5][lane=64][j=8]: W[k][n], k=kt*32+quad*8+j, n=nt*16+(lane&15)
//     W = [wQ*SCALE*LOG2E | wK | wV | 0pad] (128 x 80)
// wOf [nt=8][lane=64][j=8]: wO[k][e], k=quad*8+j (zero for k>=24)
// bqkv[80] fp32 = [bQ*SCALE*LOG2E | bK | bV | 0]
__global__ __launch_bounds__(256) void prep_kernel(
    const float* __restrict__ wQ, const float* __restrict__ bQ,
    const float* __restrict__ wK, const float* __restrict__ bK,
    const float* __restrict__ wV, const float* __restrict__ bV,
    const float* __restrict__ wO,
    unsigned short* __restrict__ Wf, unsigned short* __restrict__ wOf,
    float* __restrict__ bqkv)
{
    const int gtid   = blockIdx.x * 256 + threadIdx.x;
    const int stride = gridDim.x * 256;
    const float qs = SCALE * LOG2E;
    for (int idx = gtid; idx < 4 * 5 * 512; idx += stride) {
        const int j    = idx & 7;
        const int lane = (idx >> 3) & 63;
        const int nt   = (idx >> 9) % 5;
        const int kt   = idx / 2560;
        const int n = nt * 16 + (lane & 15);
        const int k = kt * 32 + ((lane >> 4) << 3) + j;
        float v = 0.0f;
        if (n < 24)      v = wQ[k * 24 + n] * qs;
        else if (n < 48) v = wK[k * 24 + (n - 24)];
        else if (n < 72) v = wV[k * 24 + (n - 48)];
        Wf[idx] = f2bf(v);
    }
    for (int idx = gtid; idx < 8 * 512; idx += stride) {
        const int j    = idx & 7;
        const int lane = (idx >> 3) & 63;
        const int nt   = idx >> 9;
        const int k = ((lane >> 4) << 3) + j;
        const int e = nt * 16 + (lane & 15);
        wOf[idx] = (k < 24) ? f2bf(wO[k * 128 + e]) : (unsigned short)0;
    }
    if (gtid < 80) {
        float v = 0.0f;
        if (gtid < 24)      v = bQ[gtid] * qs;
        else if (gtid < 48) v = bK[gtid - 24];
        else if (gtid < 72) v = bV[gtid - 48];
        bqkv[gtid] = v;
    }
}

// ---------------- Kernel 1: QKV projection (MFMA) ----------------
__global__ __launch_bounds__(256) void proj_kernel(
    const float* __restrict__ x, const unsigned short* __restrict__ Wf,
    const float* __restrict__ bqkv,
    unsigned short* __restrict__ Qbf, unsigned short* __restrict__ Kbf,
    unsigned short* __restrict__ Vt)
{
    __shared__ float smem[64 * OS_STRIDE];          // 21504 B, dual-purpose
    unsigned short* xs = (unsigned short*)smem;     // [64][XS_STRIDE]
    float* os = smem;                               // [64][OS_STRIDE]

    const int tid  = threadIdx.x;
    const int lane = tid & 63;
    const int w    = tid >> 6;
    const int col  = lane & 15;
    const int quad = lane >> 4;
    const int rb   = blockIdx.x * 64;

    #pragma unroll
    for (int i = 0; i < 8; ++i) {
        const int idx = i * 256 + tid;
        const int row = idx >> 5, c4 = idx & 31;
        const float4 xv = *(const float4*)(x + (size_t)(rb + row) * 128 + c4 * 4);
        uint2 h;
        h.x = pack2h(xv.x, xv.y);
        h.y = pack2h(xv.z, xv.w);
        *(uint2*)(&xs[row * XS_STRIDE + c4 * 4]) = h;
    }

    bfrag Wfr[20];
    #pragma unroll
    for (int f = 0; f < 20; ++f)
        Wfr[f] = *(const bfrag*)(Wf + (f * 64 + lane) * 8);

    __syncthreads();

    ffrag acc[5];
    #pragma unroll
    for (int nt = 0; nt < 5; ++nt) acc[nt] = (ffrag){0.f, 0.f, 0.f, 0.f};

    #pragma unroll
    for (int kt = 0; kt < 4; ++kt) {
        const bfrag Af = *(const bfrag*)(&xs[(w * 16 + col) * XS_STRIDE + kt * 32 + quad * 8]);
        #pragma unroll
        for (int nt = 0; nt < 5; ++nt)
            acc[nt] = __builtin_amdgcn_mfma_f32_16x16x32_bf16(Af, Wfr[kt * 5 + nt], acc[nt], 0, 0, 0);
    }

    __syncthreads();

    #pragma unroll
    for (int nt = 0; nt < 5; ++nt) {
        const float bb = bqkv[nt * 16 + col];
        #pragma unroll
        for (int r = 0; r < 4; ++r)
            os[(w * 16 + quad * 4 + r) * OS_STRIDE + nt * 16 + col] = acc[nt][r] + bb;
    }
    __syncthreads();

    // Q (tid<128) / K (tid>=128): row-major bf16, cols padded to 32
    {
        const int half  = tid & 1;
        const int row   = (tid >> 1) & 63;
        const int isK   = tid >> 7;
        const int cbase = isK * 24;
        unsigned int pk[8];
        #pragma unroll
        for (int g = 0; g < 8; ++g) {
            const int c0 = half * 16 + g * 2;
            const float f0 = (c0     < 24) ? os[row * OS_STRIDE + cbase + c0]     : 0.0f;
            const float f1 = (c0 + 1 < 24) ? os[row * OS_STRIDE + cbase + c0 + 1] : 0.0f;
            pk[g] = pack2h(f0, f1);
        }
        unsigned short* dst = (isK ? Kbf : Qbf) + (size_t)(rb + row) * 32 + half * 16;
        *(uint4*)(dst)     = make_uint4(pk[0], pk[1], pk[2], pk[3]);
        *(uint4*)(dst + 8) = make_uint4(pk[4], pk[5], pk[6], pk[7]);
    }

    // Vt: transposed [b][d][s], 32 d-rows per batch, 16B stores
    if (tid < 192) {
        const int d  = tid % 24;
        const int ch = tid / 24;
        unsigned int p[4];
        #pragma unroll
        for (int g = 0; g < 4; ++g) {
            const float f0 = os[(ch * 8 + g * 2 + 0) * OS_STRIDE + 48 + d];
            const float f1 = os[(ch * 8 + g * 2 + 1) * OS_STRIDE + 48 + d];
            p[g] = pack2h(f0, f1);
        }
        const int b = rb >> 12, s0 = rb & 4095;
        uint4* dst = (uint4*)(Vt + (((size_t)(b * 32 + d)) << 12) + s0 + ch * 8);
        *dst = make_uint4(p[0], p[1], p[2], p[3]);
    } else if (tid < 200) {
        // ones row d=24 (l via PV MFMA); rows 25..31 never read
        const int ch = tid - 192;
        const int b = rb >> 12, s0 = rb & 4095;
        uint4* dst = (uint4*)(Vt + (((size_t)(b * 32 + 24)) << 12) + s0 + ch * 8);
        *dst = make_uint4(0x3F803F80u, 0x3F803F80u, 0x3F803F80u, 0x3F803F80u);
    }
}

// ---------------- Kernel 2: flash attention partials ----------------
// Grid (N/128, NSP), 256 threads = 4 waves; each wave owns 32 q (2 frags).
// NO LDS, NO BARRIERS: K/V fragments loaded straight from global (L2-
// resident) in MFMA layout; key-permutation folded into per-lane base
// keyE = ((col>>2)<<3)+(col&3). V row d=24 = 1.0 -> PV MFMA computes l.
// R4: asm-volatile loads + counted vmcnt software pipeline, distance 2:
//   prologue: Q(2), L0(4), L1(4) issued
//   iter it:  issue L(it+2); s_waitcnt vmcnt(8) (retires L(it), and Q at
//             it=0); vmcnt(4) at it=14, vmcnt(0) at it=15;
//             sched_barrier(0) pins compute below the wait.
__global__ __launch_bounds__(256, 4) void attn_kernel(
    const unsigned short* __restrict__ Qbf, const unsigned short* __restrict__ Kbf,
    const unsigned short* __restrict__ Vt,
    __half* __restrict__ Opart, float* __restrict__ lpart)
{
    const int tid    = threadIdx.x;
    const int lane   = tid & 63;
    const int w      = tid >> 6;                      // 0..3
    const int col    = lane & 15;
    const int quad   = lane >> 4;
    const int blk    = blockIdx.x;                    // 0..N/128-1
    const int split  = blockIdx.y;                    // 0..NSP-1
    const int b      = blk >> 5;                      // 32 blocks per batch
    const int qbase  = blk * 128 + w * 32;            // 32 q per wave

    // K even-fragment per-lane base: key-in-32 = ((col>>2)<<3)+(col&3)
    const int keyE = ((col >> 2) << 3) + (col & 3);
    const unsigned short* Kp =
        Kbf + ((size_t)b * 4096 + (size_t)split * KCHUNK + keyE) * 32 + quad * 8;
    // V rows: Va0 d=col (0..15); Va1 d=16+col, d>24 -> ones row 24
    const int d1 = (16 + col <= 24) ? (16 + col) : 24;
    const unsigned short* Vp0 =
        Vt + ((size_t)(b * 32 + col)) * 4096 + (size_t)split * KCHUNK + quad * 8;
    const unsigned short* Vp1 =
        Vt + ((size_t)(b * 32 + d1)) * 4096 + (size_t)split * KCHUNK + quad * 8;

    // ---- software pipeline: all loads asm, issue order = source order ----
    const bfrag Qf0 = gload16(Qbf + (size_t)(qbase + col) * 32 + quad * 8);
    const bfrag Qf1 = gload16(Qbf + (size_t)(qbase + 16 + col) * 32 + quad * 8);

    bfrag vKfe[NIT], vKfo[NIT], vVa0[NIT], vVa1[NIT];
    #pragma unroll
    for (int i = 0; i < 2; ++i) {                     // prologue groups L0,L1
        vKfe[i] = gload16(Kp + i * 1024);
        vKfo[i] = gload16(Kp + i * 1024 + 128);
        vVa0[i] = gload16(Vp0 + i * 32);
        vVa1[i] = gload16(Vp1 + i * 32);
    }

    ffrag O00 = {0.f,0.f,0.f,0.f};   // frag0: O^T d = quad*4+r     (0..15)
    ffrag O01 = {0.f,0.f,0.f,0.f};   // frag0: O^T d = 16+quad*4+r  (d=24 is l)
    ffrag O10 = {0.f,0.f,0.f,0.f};   // frag1
    ffrag O11 = {0.f,0.f,0.f,0.f};

    #pragma unroll
    for (int it = 0; it < NIT; ++it) {
        // issue group L(it+2) (guard folds at compile time)
        if (it + 2 < NIT) {
            const int i = it + 2;
            vKfe[i] = gload16(Kp + i * 1024);
            vKfo[i] = gload16(Kp + i * 1024 + 128);
            vVa0[i] = gload16(Vp0 + i * 32);
            vVa1[i] = gload16(Vp1 + i * 32);
        }
        // counted wait: retire exactly group L(it) (+Q at it=0)
        if (it < NIT - 2)       asm volatile("s_waitcnt vmcnt(8)");
        else if (it == NIT - 2) asm volatile("s_waitcnt vmcnt(4)");
        else                    asm volatile("s_waitcnt vmcnt(0)");
        __builtin_amdgcn_sched_barrier(0);

        // ---- fragment 0 (q = qbase..qbase+15) ----
        {
            ffrag Se = {0.f,0.f,0.f,0.f}, So = {0.f,0.f,0.f,0.f};
            Se = __builtin_amdgcn_mfma_f32_16x16x32_bf16(vKfe[it], Qf0, Se, 0, 0, 0);
            So = __builtin_amdgcn_mfma_f32_16x16x32_bf16(vKfo[it], Qf0, So, 0, 0, 0);
            union { bfrag f; unsigned int u[4]; } P;
            P.u[0] = pack2h(__builtin_amdgcn_exp2f(Se[0]), __builtin_amdgcn_exp2f(Se[1]));
            P.u[1] = pack2h(__builtin_amdgcn_exp2f(Se[2]), __builtin_amdgcn_exp2f(Se[3]));
            P.u[2] = pack2h(__builtin_amdgcn_exp2f(So[0]), __builtin_amdgcn_exp2f(So[1]));
            P.u[3] = pack2h(__builtin_amdgcn_exp2f(So[2]), __builtin_amdgcn_exp2f(So[3]));
            O00 = __builtin_amdgcn_mfma_f32_16x16x32_bf16(vVa0[it], P.f, O00, 0, 0, 0);
            O01 = __builtin_amdgcn_mfma_f32_16x16x32_bf16(vVa1[it], P.f, O01, 0, 0, 0);
        }
        // ---- fragment 1 (q = qbase+16..qbase+31) ----
        {
            ffrag Se = {0.f,0.f,0.f,0.f}, So = {0.f,0.f,0.f,0.f};
            Se = __builtin_amdgcn_mfma_f32_16x16x32_bf16(vKfe[it], Qf1, Se, 0, 0, 0);
            So = __builtin_amdgcn_mfma_f32_16x16x32_bf16(vKfo[it], Qf1, So, 0, 0, 0);
            union { bfrag f; unsigned int u[4]; } P;
            P.u[0] = pack2h(__builtin_amdgcn_exp2f(Se[0]), __builtin_amdgcn_exp2f(Se[1]));
            P.u[1] = pack2h(__builtin_amdgcn_exp2f(Se[2]), __builtin_amdgcn_exp2f(Se[3]));
            P.u[2] = pack2h(__builtin_amdgcn_exp2f(So[0]), __builtin_amdgcn_exp2f(So[1]));
            P.u[3] = pack2h(__builtin_amdgcn_exp2f(So[2]), __builtin_amdgcn_exp2f(So[3]));
            O10 = __builtin_amdgcn_mfma_f32_16x16x32_bf16(vVa0[it], P.f, O10, 0, 0, 0);
            O11 = __builtin_amdgcn_mfma_f32_16x16x32_bf16(vVa1[it], P.f, O11, 0, 0, 0);
        }
    }

    // store fp16 partials: O^T -> Opart[q][d]; l from Ot1 d=24 (quad 2, r=0)
    {
        const size_t base0 = ((size_t)split * N_ + qbase + col) * 32;
        uint2 s0;
        s0.x = packh16(O00[0], O00[1]);
        s0.y = packh16(O00[2], O00[3]);
        *(uint2*)(Opart + base0 + quad * 4) = s0;
        if (quad < 2) {
            uint2 s1;
            s1.x = packh16(O01[0], O01[1]);
            s1.y = packh16(O01[2], O01[3]);
            *(uint2*)(Opart + base0 + 16 + quad * 4) = s1;   // d 16..23
        }
        if (quad == 2)
            lpart[(size_t)split * N_ + qbase + col] = O01[0]; // d=24 = l

        const size_t base1 = base0 + 16 * 32;
        uint2 t0;
        t0.x = packh16(O10[0], O10[1]);
        t0.y = packh16(O10[2], O10[3]);
        *(uint2*)(Opart + base1 + quad * 4) = t0;
        if (quad < 2) {
            uint2 t1;
            t1.x = packh16(O11[0], O11[1]);
            t1.y = packh16(O11[2], O11[3]);
            *(uint2*)(Opart + base1 + 16 + quad * 4) = t1;
        }
        if (quad == 2)
            lpart[(size_t)split * N_ + qbase + 16 + col] = O11[0];
    }
}

// ---------------- Kernel 3: combine + output projection ----------------
__global__ __launch_bounds__(256) void combine_kernel(
    const __half* __restrict__ Opart, const float* __restrict__ lpart,
    const unsigned short* __restrict__ wOf, const float* __restrict__ bO,
    float* __restrict__ out)
{
    __shared__ unsigned short Hs[64 * HS_STRIDE];

    const int tid = threadIdx.x;
    const int qb  = blockIdx.x * 64;
    {
        const int ql = tid >> 2;
        const int c8 = (tid & 3) * 8;     // dim chunk 0,8,16,24
        const int q  = qb + ql;
        float a[8] = {0.f, 0.f, 0.f, 0.f, 0.f, 0.f, 0.f, 0.f};
        if (c8 < 24) {                    // chunk 24..31 never written -> zeros
            #pragma unroll
            for (int s = 0; s < NSP; ++s) {
                const __half2* p2 = (const __half2*)(Opart + ((size_t)s * N_ + q) * 32 + c8);
                #pragma unroll
                for (int j = 0; j < 4; ++j) {
                    const float2 f = __half22float2(p2[j]);
                    a[2 * j]     += f.x;
                    a[2 * j + 1] += f.y;
                }
            }
        }
        float ls = 0.f;
        #pragma unroll
        for (int s = 0; s < NSP; ++s) ls += lpart[(size_t)s * N_ + q];
        const float inv = 1.0f / ls;
        uint4 pk;
        pk.x = pack2h(a[0] * inv, a[1] * inv);
        pk.y = pack2h(a[2] * inv, a[3] * inv);
        pk.z = pack2h(a[4] * inv, a[5] * inv);
        pk.w = pack2h(a[6] * inv, a[7] * inv);
        *(uint4*)(&Hs[ql * HS_STRIDE + c8]) = pk;
    }
    __syncthreads();

    const int lane = tid & 63;
    const int w    = tid >> 6;
    const int col  = lane & 15;
    const int quad = lane >> 4;
    const bfrag Hf = *(const bfrag*)(&Hs[(w * 16 + col) * HS_STRIDE + quad * 8]);
    #pragma unroll
    for (int nt = 0; nt < 8; ++nt) {
        const bfrag Wo = *(const bfrag*)(wOf + (nt * 64 + lane) * 8);
        ffrag C = {0.f, 0.f, 0.f, 0.f};
        C = __builtin_amdgcn_mfma_f32_16x16x32_bf16(Hf, Wo, C, 0, 0, 0);
        const float bo = bO[nt * 16 + col];
        #pragma unroll
        for (int r = 0; r < 4; ++r)
            out[(size_t)(qb + w * 16 + quad * 4 + r) * 128 + nt * 16 + col] = C[r] + bo;
    }
}

extern "C" void kernel_launch(void* const* d_in, const int* in_sizes, int n_in,
                              void* d_out, int out_size, void* d_ws, size_t ws_size,
                              hipStream_t stream) {
    const float* x  = (const float*)d_in[0];
    const float* wQ = (const float*)d_in[1];
    const float* bQ = (const float*)d_in[2];
    const float* wK = (const float*)d_in[3];
    const float* bK = (const float*)d_in[4];
    const float* wV = (const float*)d_in[5];
    const float* bV = (const float*)d_in[6];
    const float* wO = (const float*)d_in[7];
    const float* bO = (const float*)d_in[8];
    float* out = (float*)d_out;

    unsigned short* ws16 = (unsigned short*)d_ws;
    unsigned short* Qbf = ws16;                                    // N*32 shorts
    unsigned short* Kbf = Qbf + (size_t)N_ * 32;                   // N*32
    unsigned short* Vt  = Kbf + (size_t)N_ * 32;                   // B*32*S
    unsigned short* Wf  = Vt + (size_t)B_ * 32 * S_;               // 10240
    unsigned short* wOf = Wf + 4 * 5 * 512;                        // 4096
    float* bqkv = (float*)(wOf + 8 * 512);                         // 80 fp32
    __half* Opart = (__half*)(bqkv + 80);                          // NSP*N*32 fp16
    float* lpart = (float*)(Opart + (size_t)NSP * N_ * 32);        // NSP*N fp32

    prep_kernel<<<8, 256, 0, stream>>>(wQ, bQ, wK, bK, wV, bV, wO, Wf, wOf, bqkv);
    proj_kernel<<<N_ / 64, 256, 0, stream>>>(x, Wf, bqkv, Qbf, Kbf, Vt);
    attn_kernel<<<dim3(N_ / 128, NSP), 256, 0, stream>>>(Qbf, Kbf, Vt, Opart, lpart);
    combine_kernel<<<N_ / 64, 256, 0, stream>>>(Opart, lpart, wOf, bO, out);
}

// Round 5
// 125.435 us; speedup vs baseline: 1.1547x; 1.1143x over previous
//
#include <hip/hip_runtime.h>
#include <hip/hip_fp16.h>

// MyEncoder: B=8, S=4096, E=128, D=24, fp32 in/out.
// out = softmax((xWq+bq)(xWk+bk)^T / sqrt(128)) (xWv+bv) Wo + bo
// bf16-MFMA pipeline: prep -> proj (QKV GEMM) -> attn (flash partials,
// K-split, transposed scores, in-register P, full-K PV, MFMA-computed l)
// -> combine (sum fp16 partials + wO epilogue).
// Softmax without max-subtraction (scores tiny, shift-invariant) => K-split
// partials purely additive. exp2 with log2(e) folded into Q scale.
//
// R1-R4: direct-L2 streaming attn: latency-bound at 46-53us. Three
//   attempts to pipeline (compiler prefetch x2, inline-asm vmcnt) all
//   failed to materialize (VGPR 40-48 proves loads never stayed in
//   flight; R4's arrays hit scratch, rule #20).
// R5: revert to the PROVEN R0 LDS-staged structure, but 32 q per wave
//   (2 Q frags): each staged K/V fragment read feeds 8 MFMAs instead of
//   4 -> per-CU ds_read_b128 cycles halve (the R0 bottleneck).
//   256-thread blocks x 2048 = 8 blocks/CU (full occupancy, 64-VGPR cap),
//   8 independent blocks/CU overlap barrier/staging stalls.
//   V rows 0..24 staged from Vt (row 24 = 1.0s written by proj).

#define B_ 8
#define S_ 4096
#define E_ 128
#define D_ 24
#define N_ (B_ * S_)               // 32768 rows
#define SCALE 0.08838834764831845f // 1/sqrt(128)
#define LOG2E 1.4426950408889634f

#define NSP 8                      // K-splits (compile-time)
#define KCHUNK (S_ / NSP)          // 512 keys per split
#define TK 128                     // keys per LDS tile

#define KS_STRIDE 40               // K_s row stride (shorts)
#define VS_STRIDE 136              // V_s row stride (shorts): 128 + 8 pad
#define HS_STRIDE 40               // H_s row stride in combine
#define XS_STRIDE 136              // x_s row stride (bf16) in proj
#define OS_STRIDE 84               // out_s row stride (fp32) in proj

typedef __attribute__((ext_vector_type(8))) short bfrag;   // 8 bf16 = 4 VGPR
typedef __attribute__((ext_vector_type(4))) float ffrag;   // 4 fp32 acc

__device__ inline unsigned short f2bf(float f) {           // RNE fp32->bf16
    unsigned int x = __builtin_bit_cast(unsigned int, f);
    return (unsigned short)((x + 0x7fffu + ((x >> 16) & 1u)) >> 16);
}
// round-half-up bf16 pair pack: 2 int-adds + v_perm (validated on HW)
__device__ inline unsigned int pack2h(float a, float b) {
    unsigned int ua = __builtin_bit_cast(unsigned int, a) + 0x8000u;
    unsigned int ub = __builtin_bit_cast(unsigned int, b) + 0x8000u;
    return __builtin_amdgcn_perm(ub, ua, 0x07060302);      // [b.hi16 | a.hi16]
}
// fp16 pair pack, RTZ, single v_cvt_pkrtz_f16_f32
__device__ inline unsigned int packh16(float a, float b) {
    return __builtin_bit_cast(unsigned int, __builtin_amdgcn_cvt_pkrtz(a, b));
}

// ---------------- Kernel 0: weight prep (8 blocks) ----------------
// Wf  [kt=4][nt=5][lane=64][j=8]: W[k][n], k=kt*32+quad*8+j, n=nt*16+(lane&15)
//     W = [wQ*SCALE*LOG2E | wK | wV | 0pad] (128 x 80)
// wOf [nt=8][lane=64][j=8]: wO[k][e], k=quad*8+j (zero for k>=24)
// bqkv[80] fp32 = [bQ*SCALE*LOG2E | bK | bV | 0]
__global__ __launch_bounds__(256) void prep_kernel(
    const float* __restrict__ wQ, const float* __restrict__ bQ,
    const float* __restrict__ wK, const float* __restrict__ bK,
    const float* __restrict__ wV, const float* __restrict__ bV,
    const float* __restrict__ wO,
    unsigned short* __restrict__ Wf, unsigned short* __restrict__ wOf,
    float* __restrict__ bqkv)
{
    const int gtid   = blockIdx.x * 256 + threadIdx.x;
    const int stride = gridDim.x * 256;
    const float qs = SCALE * LOG2E;
    for (int idx = gtid; idx < 4 * 5 * 512; idx += stride) {
        const int j    = idx & 7;
        const int lane = (idx >> 3) & 63;
        const int nt   = (idx >> 9) % 5;
        const int kt   = idx / 2560;
        const int n = nt * 16 + (lane & 15);
        const int k = kt * 32 + ((lane >> 4) << 3) + j;
        float v = 0.0f;
        if (n < 24)      v = wQ[k * 24 + n] * qs;
        else if (n < 48) v = wK[k * 24 + (n - 24)];
        else if (n < 72) v = wV[k * 24 + (n - 48)];
        Wf[idx] = f2bf(v);
    }
    for (int idx = gtid; idx < 8 * 512; idx += stride) {
        const int j    = idx & 7;
        const int lane = (idx >> 3) & 63;
        const int nt   = idx >> 9;
        const int k = ((lane >> 4) << 3) + j;
        const int e = nt * 16 + (lane & 15);
        wOf[idx] = (k < 24) ? f2bf(wO[k * 128 + e]) : (unsigned short)0;
    }
    if (gtid < 80) {
        float v = 0.0f;
        if (gtid < 24)      v = bQ[gtid] * qs;
        else if (gtid < 48) v = bK[gtid - 24];
        else if (gtid < 72) v = bV[gtid - 48];
        bqkv[gtid] = v;
    }
}

// ---------------- Kernel 1: QKV projection (MFMA) ----------------
__global__ __launch_bounds__(256) void proj_kernel(
    const float* __restrict__ x, const unsigned short* __restrict__ Wf,
    const float* __restrict__ bqkv,
    unsigned short* __restrict__ Qbf, unsigned short* __restrict__ Kbf,
    unsigned short* __restrict__ Vt)
{
    __shared__ float smem[64 * OS_STRIDE];          // 21504 B, dual-purpose
    unsigned short* xs = (unsigned short*)smem;     // [64][XS_STRIDE]
    float* os = smem;                               // [64][OS_STRIDE]

    const int tid  = threadIdx.x;
    const int lane = tid & 63;
    const int w    = tid >> 6;
    const int col  = lane & 15;
    const int quad = lane >> 4;
    const int rb   = blockIdx.x * 64;

    #pragma unroll
    for (int i = 0; i < 8; ++i) {
        const int idx = i * 256 + tid;
        const int row = idx >> 5, c4 = idx & 31;
        const float4 xv = *(const float4*)(x + (size_t)(rb + row) * 128 + c4 * 4);
        uint2 h;
        h.x = pack2h(xv.x, xv.y);
        h.y = pack2h(xv.z, xv.w);
        *(uint2*)(&xs[row * XS_STRIDE + c4 * 4]) = h;
    }

    bfrag Wfr[20];
    #pragma unroll
    for (int f = 0; f < 20; ++f)
        Wfr[f] = *(const bfrag*)(Wf + (f * 64 + lane) * 8);

    __syncthreads();

    ffrag acc[5];
    #pragma unroll
    for (int nt = 0; nt < 5; ++nt) acc[nt] = (ffrag){0.f, 0.f, 0.f, 0.f};

    #pragma unroll
    for (int kt = 0; kt < 4; ++kt) {
        const bfrag Af = *(const bfrag*)(&xs[(w * 16 + col) * XS_STRIDE + kt * 32 + quad * 8]);
        #pragma unroll
        for (int nt = 0; nt < 5; ++nt)
            acc[nt] = __builtin_amdgcn_mfma_f32_16x16x32_bf16(Af, Wfr[kt * 5 + nt], acc[nt], 0, 0, 0);
    }

    __syncthreads();

    #pragma unroll
    for (int nt = 0; nt < 5; ++nt) {
        const float bb = bqkv[nt * 16 + col];
        #pragma unroll
        for (int r = 0; r < 4; ++r)
            os[(w * 16 + quad * 4 + r) * OS_STRIDE + nt * 16 + col] = acc[nt][r] + bb;
    }
    __syncthreads();

    // Q (tid<128) / K (tid>=128): row-major bf16, cols padded to 32
    {
        const int half  = tid & 1;
        const int row   = (tid >> 1) & 63;
        const int isK   = tid >> 7;
        const int cbase = isK * 24;
        unsigned int pk[8];
        #pragma unroll
        for (int g = 0; g < 8; ++g) {
            const int c0 = half * 16 + g * 2;
            const float f0 = (c0     < 24) ? os[row * OS_STRIDE + cbase + c0]     : 0.0f;
            const float f1 = (c0 + 1 < 24) ? os[row * OS_STRIDE + cbase + c0 + 1] : 0.0f;
            pk[g] = pack2h(f0, f1);
        }
        unsigned short* dst = (isK ? Kbf : Qbf) + (size_t)(rb + row) * 32 + half * 16;
        *(uint4*)(dst)     = make_uint4(pk[0], pk[1], pk[2], pk[3]);
        *(uint4*)(dst + 8) = make_uint4(pk[4], pk[5], pk[6], pk[7]);
    }

    // Vt: transposed [b][d][s], 32 d-rows per batch, 16B stores
    if (tid < 192) {
        const int d  = tid % 24;
        const int ch = tid / 24;
        unsigned int p[4];
        #pragma unroll
        for (int g = 0; g < 4; ++g) {
            const float f0 = os[(ch * 8 + g * 2 + 0) * OS_STRIDE + 48 + d];
            const float f1 = os[(ch * 8 + g * 2 + 1) * OS_STRIDE + 48 + d];
            p[g] = pack2h(f0, f1);
        }
        const int b = rb >> 12, s0 = rb & 4095;
        uint4* dst = (uint4*)(Vt + (((size_t)(b * 32 + d)) << 12) + s0 + ch * 8);
        *dst = make_uint4(p[0], p[1], p[2], p[3]);
    } else if (tid < 200) {
        // ones row d=24 (l via PV MFMA); rows 25..31 never read
        const int ch = tid - 192;
        const int b = rb >> 12, s0 = rb & 4095;
        uint4* dst = (uint4*)(Vt + (((size_t)(b * 32 + 24)) << 12) + s0 + ch * 8);
        *dst = make_uint4(0x3F803F80u, 0x3F803F80u, 0x3F803F80u, 0x3F803F80u);
    }
}

// ---------------- Kernel 2: flash attention partials ----------------
// Grid (N/128, NSP), 256 threads = 4 waves; each wave owns 32 q (2 Q
// fragments) -> each staged K/V fragment read feeds 8 MFMAs (2x R0).
// K staged permuted: key k -> row (k&~31)+(((k>>2)&1)<<4)+(((k&31)>>3)<<2)+(k&3)
// so chunk 2*c2 gives keys quad*8+r, chunk 2*c2+1 gives quad*8+4+r -> one
// full K=32 P fragment per 32 keys. V natural order, rows 0..24 staged
// (row 24 = 1.0 from proj) so the PV MFMA computes l in O*1's d=24 elem;
// Va1 lanes with d>24 redirected to row 24. 2048 blocks = 8/CU: barrier
// and staging stalls overlap across independent blocks.
__global__ __launch_bounds__(256, 8) void attn_kernel(
    const unsigned short* __restrict__ Qbf, const unsigned short* __restrict__ Kbf,
    const unsigned short* __restrict__ Vt,
    __half* __restrict__ Opart, float* __restrict__ lpart)
{
    __shared__ unsigned short Ks[TK * KS_STRIDE];     // 10240 B
    __shared__ unsigned short Vs[25 * VS_STRIDE];     // 6800 B

    const int tid   = threadIdx.x;
    const int lane  = tid & 63;
    const int w     = tid >> 6;                       // 0..3
    const int col   = lane & 15;
    const int quad  = lane >> 4;
    const int blk   = blockIdx.x;                     // 0..N/128-1
    const int split = blockIdx.y;                     // 0..NSP-1
    const int b     = blk >> 5;                       // 32 blocks per batch
    const int qbase = blk * 128 + w * 32;             // 32 q per wave

    // two Q fragments (B-operand: lane holds Q[q=col][k=quad*8+j])
    const bfrag Qf0 = *(const bfrag*)(Qbf + (size_t)(qbase + col) * 32 + quad * 8);
    const bfrag Qf1 = *(const bfrag*)(Qbf + (size_t)(qbase + 16 + col) * 32 + quad * 8);

    const unsigned short* Kbase = Kbf + ((size_t)b * 4096 + split * KCHUNK) * 32;
    const unsigned short* Vbase = Vt + (size_t)(b * 32) * 4096 + split * KCHUNK;

    // Va1 V-row: d = 16+col, clamped to ones row 24 for col>8
    const int r1 = (16 + col <= 24) ? (16 + col) : 24;

    ffrag O00 = {0.f,0.f,0.f,0.f};   // frag0: O^T d = quad*4+r     (0..15)
    ffrag O01 = {0.f,0.f,0.f,0.f};   // frag0: O^T d = 16+quad*4+r  (d=24 is l)
    ffrag O10 = {0.f,0.f,0.f,0.f};   // frag1
    ffrag O11 = {0.f,0.f,0.f,0.f};

    for (int kb = 0; kb < KCHUNK; kb += TK) {
        // K tile: permuted rows, 128 keys x 32 bf16 (512 x 16B, 2/thread)
        #pragma unroll
        for (int i = 0; i < 2; ++i) {
            const int idx = i * 256 + tid;
            const int key = idx >> 2, ch = idx & 3;
            const uint4 t4 = *(const uint4*)(Kbase + (size_t)(kb + key) * 32 + ch * 8);
            const int row = (key & ~31) + (((key >> 2) & 1) << 4)
                          + (((key & 31) >> 3) << 2) + (key & 3);
            *(uint4*)(&Ks[row * KS_STRIDE + ch * 8]) = t4;
        }
        // V tile: 25 d-rows x 128 keys, natural order (400 x 16B)
        #pragma unroll
        for (int i = 0; i < 2; ++i) {
            const int idx = i * 256 + tid;
            if (idx < 400) {
                const int d = idx >> 4, ch = idx & 15;
                const uint4 t4 = *(const uint4*)(Vbase + (size_t)d * 4096 + kb + ch * 8);
                *(uint4*)(&Vs[d * VS_STRIDE + ch * 8]) = t4;
            }
        }
        __syncthreads();

        #pragma unroll
        for (int c2 = 0; c2 < 4; ++c2) {
            const bfrag Kfe = *(const bfrag*)(&Ks[(c2 * 32 + col) * KS_STRIDE + quad * 8]);
            const bfrag Kfo = *(const bfrag*)(&Ks[(c2 * 32 + 16 + col) * KS_STRIDE + quad * 8]);
            const bfrag Va0 = *(const bfrag*)(&Vs[col * VS_STRIDE + c2 * 32 + quad * 8]);
            const bfrag Va1 = *(const bfrag*)(&Vs[r1 * VS_STRIDE + c2 * 32 + quad * 8]);

            // ---- fragment 0 (q = qbase..qbase+15) ----
            {
                ffrag Se = {0.f,0.f,0.f,0.f}, So = {0.f,0.f,0.f,0.f};
                Se = __builtin_amdgcn_mfma_f32_16x16x32_bf16(Kfe, Qf0, Se, 0, 0, 0);
                So = __builtin_amdgcn_mfma_f32_16x16x32_bf16(Kfo, Qf0, So, 0, 0, 0);
                union { bfrag f; unsigned int u[4]; } P;
                P.u[0] = pack2h(__builtin_amdgcn_exp2f(Se[0]), __builtin_amdgcn_exp2f(Se[1]));
                P.u[1] = pack2h(__builtin_amdgcn_exp2f(Se[2]), __builtin_amdgcn_exp2f(Se[3]));
                P.u[2] = pack2h(__builtin_amdgcn_exp2f(So[0]), __builtin_amdgcn_exp2f(So[1]));
                P.u[3] = pack2h(__builtin_amdgcn_exp2f(So[2]), __builtin_amdgcn_exp2f(So[3]));
                O00 = __builtin_amdgcn_mfma_f32_16x16x32_bf16(Va0, P.f, O00, 0, 0, 0);
                O01 = __builtin_amdgcn_mfma_f32_16x16x32_bf16(Va1, P.f, O01, 0, 0, 0);
            }
            // ---- fragment 1 (q = qbase+16..qbase+31) ----
            {
                ffrag Se = {0.f,0.f,0.f,0.f}, So = {0.f,0.f,0.f,0.f};
                Se = __builtin_amdgcn_mfma_f32_16x16x32_bf16(Kfe, Qf1, Se, 0, 0, 0);
                So = __builtin_amdgcn_mfma_f32_16x16x32_bf16(Kfo, Qf1, So, 0, 0, 0);
                union { bfrag f; unsigned int u[4]; } P;
                P.u[0] = pack2h(__builtin_amdgcn_exp2f(Se[0]), __builtin_amdgcn_exp2f(Se[1]));
                P.u[1] = pack2h(__builtin_amdgcn_exp2f(Se[2]), __builtin_amdgcn_exp2f(Se[3]));
                P.u[2] = pack2h(__builtin_amdgcn_exp2f(So[0]), __builtin_amdgcn_exp2f(So[1]));
                P.u[3] = pack2h(__builtin_amdgcn_exp2f(So[2]), __builtin_amdgcn_exp2f(So[3]));
                O10 = __builtin_amdgcn_mfma_f32_16x16x32_bf16(Va0, P.f, O10, 0, 0, 0);
                O11 = __builtin_amdgcn_mfma_f32_16x16x32_bf16(Va1, P.f, O11, 0, 0, 0);
            }
        }
        __syncthreads();
    }

    // store fp16 partials: O^T -> Opart[q][d]; l from O*1 d=24 (quad 2, r=0)
    {
        const size_t base0 = ((size_t)split * N_ + qbase + col) * 32;
        uint2 s0;
        s0.x = packh16(O00[0], O00[1]);
        s0.y = packh16(O00[2], O00[3]);
        *(uint2*)(Opart + base0 + quad * 4) = s0;
        if (quad < 2) {
            uint2 s1;
            s1.x = packh16(O01[0], O01[1]);
            s1.y = packh16(O01[2], O01[3]);
            *(uint2*)(Opart + base0 + 16 + quad * 4) = s1;   // d 16..23
        }
        if (quad == 2)
            lpart[(size_t)split * N_ + qbase + col] = O01[0]; // d=24 = l

        const size_t base1 = base0 + 16 * 32;
        uint2 t0;
        t0.x = packh16(O10[0], O10[1]);
        t0.y = packh16(O10[2], O10[3]);
        *(uint2*)(Opart + base1 + quad * 4) = t0;
        if (quad < 2) {
            uint2 t1;
            t1.x = packh16(O11[0], O11[1]);
            t1.y = packh16(O11[2], O11[3]);
            *(uint2*)(Opart + base1 + 16 + quad * 4) = t1;
        }
        if (quad == 2)
            lpart[(size_t)split * N_ + qbase + 16 + col] = O11[0];
    }
}

// ---------------- Kernel 3: combine + output projection ----------------
__global__ __launch_bounds__(256) void combine_kernel(
    const __half* __restrict__ Opart, const float* __restrict__ lpart,
    const unsigned short* __restrict__ wOf, const float* __restrict__ bO,
    float* __restrict__ out)
{
    __shared__ unsigned short Hs[64 * HS_STRIDE];

    const int tid = threadIdx.x;
    const int qb  = blockIdx.x * 64;
    {
        const int ql = tid >> 2;
        const int c8 = (tid & 3) * 8;     // dim chunk 0,8,16,24
        const int q  = qb + ql;
        float a[8] = {0.f, 0.f, 0.f, 0.f, 0.f, 0.f, 0.f, 0.f};
        if (c8 < 24) {                    // chunk 24..31 never written -> zeros
            #pragma unroll
            for (int s = 0; s < NSP; ++s) {
                const __half2* p2 = (const __half2*)(Opart + ((size_t)s * N_ + q) * 32 + c8);
                #pragma unroll
                for (int j = 0; j < 4; ++j) {
                    const float2 f = __half22float2(p2[j]);
                    a[2 * j]     += f.x;
                    a[2 * j + 1] += f.y;
                }
            }
        }
        float ls = 0.f;
        #pragma unroll
        for (int s = 0; s < NSP; ++s) ls += lpart[(size_t)s * N_ + q];
        const float inv = 1.0f / ls;
        uint4 pk;
        pk.x = pack2h(a[0] * inv, a[1] * inv);
        pk.y = pack2h(a[2] * inv, a[3] * inv);
        pk.z = pack2h(a[4] * inv, a[5] * inv);
        pk.w = pack2h(a[6] * inv, a[7] * inv);
        *(uint4*)(&Hs[ql * HS_STRIDE + c8]) = pk;
    }
    __syncthreads();

    const int lane = tid & 63;
    const int w    = tid >> 6;
    const int col  = lane & 15;
    const int quad = lane >> 4;
    const bfrag Hf = *(const bfrag*)(&Hs[(w * 16 + col) * HS_STRIDE + quad * 8]);
    #pragma unroll
    for (int nt = 0; nt < 8; ++nt) {
        const bfrag Wo = *(const bfrag*)(wOf + (nt * 64 + lane) * 8);
        ffrag C = {0.f, 0.f, 0.f, 0.f};
        C = __builtin_amdgcn_mfma_f32_16x16x32_bf16(Hf, Wo, C, 0, 0, 0);
        const float bo = bO[nt * 16 + col];
        #pragma unroll
        for (int r = 0; r < 4; ++r)
            out[(size_t)(qb + w * 16 + quad * 4 + r) * 128 + nt * 16 + col] = C[r] + bo;
    }
}

extern "C" void kernel_launch(void* const* d_in, const int* in_sizes, int n_in,
                              void* d_out, int out_size, void* d_ws, size_t ws_size,
                              hipStream_t stream) {
    const float* x  = (const float*)d_in[0];
    const float* wQ = (const float*)d_in[1];
    const float* bQ = (const float*)d_in[2];
    const float* wK = (const float*)d_in[3];
    const float* bK = (const float*)d_in[4];
    const float* wV = (const float*)d_in[5];
    const float* bV = (const float*)d_in[6];
    const float* wO = (const float*)d_in[7];
    const float* bO = (const float*)d_in[8];
    float* out = (float*)d_out;

    unsigned short* ws16 = (unsigned short*)d_ws;
    unsigned short* Qbf = ws16;                                    // N*32 shorts
    unsigned short* Kbf = Qbf + (size_t)N_ * 32;                   // N*32
    unsigned short* Vt  = Kbf + (size_t)N_ * 32;                   // B*32*S
    unsigned short* Wf  = Vt + (size_t)B_ * 32 * S_;               // 10240
    unsigned short* wOf = Wf + 4 * 5 * 512;                        // 4096
    float* bqkv = (float*)(wOf + 8 * 512);                         // 80 fp32
    __half* Opart = (__half*)(bqkv + 80);                          // NSP*N*32 fp16
    float* lpart = (float*)(Opart + (size_t)NSP * N_ * 32);        // NSP*N fp32

    prep_kernel<<<8, 256, 0, stream>>>(wQ, bQ, wK, bK, wV, bV, wO, Wf, wOf, bqkv);
    proj_kernel<<<N_ / 64, 256, 0, stream>>>(x, Wf, bqkv, Qbf, Kbf, Vt);
    attn_kernel<<<dim3(N_ / 128, NSP), 256, 0, stream>>>(Qbf, Kbf, Vt, Opart, lpart);
    combine_kernel<<<N_ / 64, 256, 0, stream>>>(Opart, lpart, wOf, bO, out);
}

// Round 6
// 119.321 us; speedup vs baseline: 1.2139x; 1.0512x over previous
//
#include <hip/hip_runtime.h>
#include <hip/hip_fp16.h>

// MyEncoder: B=8, S=4096, E=128, D=24, fp32 in/out.
// out = softmax((xWq+bq)(xWk+bk)^T / sqrt(128)) (xWv+bv) Wo + bo
// bf16-MFMA pipeline: prep -> proj (QKV GEMM) -> attn (flash partials,
// K-split, transposed scores, in-register P, full-K PV, MFMA-computed l)
// -> combine (sum fp16 partials + wO epilogue).
// Softmax without max-subtraction (scores tiny, shift-invariant) => K-split
// partials purely additive. exp2 with log2(e) folded into Q scale.
//
// R1-R4: direct-L2 streaming attn: latency-bound 46-53us (3 pipeline
//   attempts failed; compiler sank loads / arrays hit scratch).
// R5: LDS-staged, 32 q/wave, 4-wave blocks, NSP=8 -> attn ~33us. Work
//   floor is ~14us (exp2 6.8 + VALU 3.6 + MFMA 2 + staging); the ~20us
//   slack is stage->barrier->compute->barrier serialization.
// R6: minimum-2-phase double-buffer (T14 async-STAGE split, HW-verified
//   pattern): per tile {issue next-tile loads to regs, sched_barrier(0),
//   compute current from LDS, vmcnt-gated ds_write to other buffer, ONE
//   __syncthreads}. 512-thread blocks (8 waves x 32q = 256 q), NSP=4:
//   staging amortized 2x, Opart traffic halved, 2 blocks/CU.

#define B_ 8
#define S_ 4096
#define E_ 128
#define D_ 24
#define N_ (B_ * S_)               // 32768 rows
#define SCALE 0.08838834764831845f // 1/sqrt(128)
#define LOG2E 1.4426950408889634f

#define NSP 4                      // K-splits (compile-time)
#define KCHUNK (S_ / NSP)          // 1024 keys per split
#define TK 128                     // keys per LDS tile
#define NT (KCHUNK / TK)           // 8 tiles per split

#define KS_STRIDE 40               // K_s row stride (shorts)
#define VS_STRIDE 136              // V_s row stride (shorts): 128 + 8 pad
#define HS_STRIDE 40               // H_s row stride in combine
#define XS_STRIDE 136              // x_s row stride (bf16) in proj
#define OS_STRIDE 84               // out_s row stride (fp32) in proj

typedef __attribute__((ext_vector_type(8))) short bfrag;   // 8 bf16 = 4 VGPR
typedef __attribute__((ext_vector_type(4))) float ffrag;   // 4 fp32 acc

__device__ inline unsigned short f2bf(float f) {           // RNE fp32->bf16
    unsigned int x = __builtin_bit_cast(unsigned int, f);
    return (unsigned short)((x + 0x7fffu + ((x >> 16) & 1u)) >> 16);
}
// round-half-up bf16 pair pack: 2 int-adds + v_perm (validated on HW)
__device__ inline unsigned int pack2h(float a, float b) {
    unsigned int ua = __builtin_bit_cast(unsigned int, a) + 0x8000u;
    unsigned int ub = __builtin_bit_cast(unsigned int, b) + 0x8000u;
    return __builtin_amdgcn_perm(ub, ua, 0x07060302);      // [b.hi16 | a.hi16]
}
// fp16 pair pack, RTZ, single v_cvt_pkrtz_f16_f32
__device__ inline unsigned int packh16(float a, float b) {
    return __builtin_bit_cast(unsigned int, __builtin_amdgcn_cvt_pkrtz(a, b));
}

// ---------------- Kernel 0: weight prep (8 blocks) ----------------
// Wf  [kt=4][nt=5][lane=64][j=8]: W[k][n], k=kt*32+quad*8+j, n=nt*16+(lane&15)
//     W = [wQ*SCALE*LOG2E | wK | wV | 0pad] (128 x 80)
// wOf [nt=8][lane=64][j=8]: wO[k][e], k=quad*8+j (zero for k>=24)
// bqkv[80] fp32 = [bQ*SCALE*LOG2E | bK | bV | 0]
__global__ __launch_bounds__(256) void prep_kernel(
    const float* __restrict__ wQ, const float* __restrict__ bQ,
    const float* __restrict__ wK, const float* __restrict__ bK,
    const float* __restrict__ wV, const float* __restrict__ bV,
    const float* __restrict__ wO,
    unsigned short* __restrict__ Wf, unsigned short* __restrict__ wOf,
    float* __restrict__ bqkv)
{
    const int gtid   = blockIdx.x * 256 + threadIdx.x;
    const int stride = gridDim.x * 256;
    const float qs = SCALE * LOG2E;
    for (int idx = gtid; idx < 4 * 5 * 512; idx += stride) {
        const int j    = idx & 7;
        const int lane = (idx >> 3) & 63;
        const int nt   = (idx >> 9) % 5;
        const int kt   = idx / 2560;
        const int n = nt * 16 + (lane & 15);
        const int k = kt * 32 + ((lane >> 4) << 3) + j;
        float v = 0.0f;
        if (n < 24)      v = wQ[k * 24 + n] * qs;
        else if (n < 48) v = wK[k * 24 + (n - 24)];
        else if (n < 72) v = wV[k * 24 + (n - 48)];
        Wf[idx] = f2bf(v);
    }
    for (int idx = gtid; idx < 8 * 512; idx += stride) {
        const int j    = idx & 7;
        const int lane = (idx >> 3) & 63;
        const int nt   = idx >> 9;
        const int k = ((lane >> 4) << 3) + j;
        const int e = nt * 16 + (lane & 15);
        wOf[idx] = (k < 24) ? f2bf(wO[k * 128 + e]) : (unsigned short)0;
    }
    if (gtid < 80) {
        float v = 0.0f;
        if (gtid < 24)      v = bQ[gtid] * qs;
        else if (gtid < 48) v = bK[gtid - 24];
        else if (gtid < 72) v = bV[gtid - 48];
        bqkv[gtid] = v;
    }
}

// ---------------- Kernel 1: QKV projection (MFMA) ----------------
__global__ __launch_bounds__(256) void proj_kernel(
    const float* __restrict__ x, const unsigned short* __restrict__ Wf,
    const float* __restrict__ bqkv,
    unsigned short* __restrict__ Qbf, unsigned short* __restrict__ Kbf,
    unsigned short* __restrict__ Vt)
{
    __shared__ float smem[64 * OS_STRIDE];          // 21504 B, dual-purpose
    unsigned short* xs = (unsigned short*)smem;     // [64][XS_STRIDE]
    float* os = smem;                               // [64][OS_STRIDE]

    const int tid  = threadIdx.x;
    const int lane = tid & 63;
    const int w    = tid >> 6;
    const int col  = lane & 15;
    const int quad = lane >> 4;
    const int rb   = blockIdx.x * 64;

    #pragma unroll
    for (int i = 0; i < 8; ++i) {
        const int idx = i * 256 + tid;
        const int row = idx >> 5, c4 = idx & 31;
        const float4 xv = *(const float4*)(x + (size_t)(rb + row) * 128 + c4 * 4);
        uint2 h;
        h.x = pack2h(xv.x, xv.y);
        h.y = pack2h(xv.z, xv.w);
        *(uint2*)(&xs[row * XS_STRIDE + c4 * 4]) = h;
    }

    bfrag Wfr[20];
    #pragma unroll
    for (int f = 0; f < 20; ++f)
        Wfr[f] = *(const bfrag*)(Wf + (f * 64 + lane) * 8);

    __syncthreads();

    ffrag acc[5];
    #pragma unroll
    for (int nt = 0; nt < 5; ++nt) acc[nt] = (ffrag){0.f, 0.f, 0.f, 0.f};

    #pragma unroll
    for (int kt = 0; kt < 4; ++kt) {
        const bfrag Af = *(const bfrag*)(&xs[(w * 16 + col) * XS_STRIDE + kt * 32 + quad * 8]);
        #pragma unroll
        for (int nt = 0; nt < 5; ++nt)
            acc[nt] = __builtin_amdgcn_mfma_f32_16x16x32_bf16(Af, Wfr[kt * 5 + nt], acc[nt], 0, 0, 0);
    }

    __syncthreads();

    #pragma unroll
    for (int nt = 0; nt < 5; ++nt) {
        const float bb = bqkv[nt * 16 + col];
        #pragma unroll
        for (int r = 0; r < 4; ++r)
            os[(w * 16 + quad * 4 + r) * OS_STRIDE + nt * 16 + col] = acc[nt][r] + bb;
    }
    __syncthreads();

    // Q (tid<128) / K (tid>=128): row-major bf16, cols padded to 32
    {
        const int half  = tid & 1;
        const int row   = (tid >> 1) & 63;
        const int isK   = tid >> 7;
        const int cbase = isK * 24;
        unsigned int pk[8];
        #pragma unroll
        for (int g = 0; g < 8; ++g) {
            const int c0 = half * 16 + g * 2;
            const float f0 = (c0     < 24) ? os[row * OS_STRIDE + cbase + c0]     : 0.0f;
            const float f1 = (c0 + 1 < 24) ? os[row * OS_STRIDE + cbase + c0 + 1] : 0.0f;
            pk[g] = pack2h(f0, f1);
        }
        unsigned short* dst = (isK ? Kbf : Qbf) + (size_t)(rb + row) * 32 + half * 16;
        *(uint4*)(dst)     = make_uint4(pk[0], pk[1], pk[2], pk[3]);
        *(uint4*)(dst + 8) = make_uint4(pk[4], pk[5], pk[6], pk[7]);
    }

    // Vt: transposed [b][d][s], 32 d-rows per batch, 16B stores
    if (tid < 192) {
        const int d  = tid % 24;
        const int ch = tid / 24;
        unsigned int p[4];
        #pragma unroll
        for (int g = 0; g < 4; ++g) {
            const float f0 = os[(ch * 8 + g * 2 + 0) * OS_STRIDE + 48 + d];
            const float f1 = os[(ch * 8 + g * 2 + 1) * OS_STRIDE + 48 + d];
            p[g] = pack2h(f0, f1);
        }
        const int b = rb >> 12, s0 = rb & 4095;
        uint4* dst = (uint4*)(Vt + (((size_t)(b * 32 + d)) << 12) + s0 + ch * 8);
        *dst = make_uint4(p[0], p[1], p[2], p[3]);
    } else if (tid < 200) {
        // ones row d=24 (l via PV MFMA); rows 25..31 never read
        const int ch = tid - 192;
        const int b = rb >> 12, s0 = rb & 4095;
        uint4* dst = (uint4*)(Vt + (((size_t)(b * 32 + 24)) << 12) + s0 + ch * 8);
        *dst = make_uint4(0x3F803F80u, 0x3F803F80u, 0x3F803F80u, 0x3F803F80u);
    }
}

// ---------------- Kernel 2: flash attention partials ----------------
// Grid (N/256, NSP), 512 threads = 8 waves; each wave owns 32 q (2 Q
// fragments) -> each staged K/V fragment read feeds 8 MFMAs.
// K staged permuted: key k -> row (k&~31)+(((k>>2)&1)<<4)+(((k&31)>>3)<<2)+(k&3)
// so chunk 2*c2 gives keys quad*8+r, chunk 2*c2+1 gives quad*8+4+r -> one
// full K=32 P fragment per 32 keys. V natural order, rows 0..24 staged
// (row 24 = 1.0 from proj) so the PV MFMA computes l in O*1's d=24 elem;
// Va1 lanes with d>24 redirected to row 24.
// R6: double-buffered LDS, ONE barrier per tile (T14 async-STAGE):
//   {issue next-tile loads -> regs; sched_barrier(0); compute current
//    tile; ds_write regs -> other buffer (vmcnt auto); __syncthreads}.
__global__ __launch_bounds__(512, 4) void attn_kernel(
    const unsigned short* __restrict__ Qbf, const unsigned short* __restrict__ Kbf,
    const unsigned short* __restrict__ Vt,
    __half* __restrict__ Opart, float* __restrict__ lpart)
{
    __shared__ unsigned short Ks[2 * TK * KS_STRIDE];   // 20480 B
    __shared__ unsigned short Vs[2 * 25 * VS_STRIDE];   // 13600 B

    const int tid   = threadIdx.x;
    const int lane  = tid & 63;
    const int w     = tid >> 6;                       // 0..7
    const int col   = lane & 15;
    const int quad  = lane >> 4;
    const int blk   = blockIdx.x;                     // 0..N/256-1
    const int split = blockIdx.y;                     // 0..NSP-1
    const int b     = blk >> 4;                       // 16 blocks per batch
    const int qbase = blk * 256 + w * 32;             // 32 q per wave

    // two Q fragments (B-operand: lane holds Q[q=col][k=quad*8+j])
    const bfrag Qf0 = *(const bfrag*)(Qbf + (size_t)(qbase + col) * 32 + quad * 8);
    const bfrag Qf1 = *(const bfrag*)(Qbf + (size_t)(qbase + 16 + col) * 32 + quad * 8);

    const unsigned short* Kbase = Kbf + ((size_t)b * 4096 + split * KCHUNK) * 32;
    const unsigned short* Vbase = Vt + (size_t)(b * 32) * 4096 + split * KCHUNK;

    // staging roles (fixed per thread)
    const int skey = tid >> 2, sch = tid & 3;         // K: 512 x 16B
    const int srow = (skey & ~31) + (((skey >> 2) & 1) << 4)
                   + (((skey & 31) >> 3) << 2) + (skey & 3);
    const int sd = tid >> 4, svch = tid & 15;         // V: 400 x 16B (tid<400)

    // Va1 V-row: d = 16+col, clamped to ones row 24 for col>8
    const int r1 = (16 + col <= 24) ? (16 + col) : 24;

    ffrag O00 = {0.f,0.f,0.f,0.f};   // frag0: O^T d = quad*4+r     (0..15)
    ffrag O01 = {0.f,0.f,0.f,0.f};   // frag0: O^T d = 16+quad*4+r  (d=24 is l)
    ffrag O10 = {0.f,0.f,0.f,0.f};   // frag1
    ffrag O11 = {0.f,0.f,0.f,0.f};

    auto compute_tile = [&](const unsigned short* ksb, const unsigned short* vsb) {
        #pragma unroll
        for (int c2 = 0; c2 < 4; ++c2) {
            const bfrag Kfe = *(const bfrag*)(&ksb[(c2 * 32 + col) * KS_STRIDE + quad * 8]);
            const bfrag Kfo = *(const bfrag*)(&ksb[(c2 * 32 + 16 + col) * KS_STRIDE + quad * 8]);
            const bfrag Va0 = *(const bfrag*)(&vsb[col * VS_STRIDE + c2 * 32 + quad * 8]);
            const bfrag Va1 = *(const bfrag*)(&vsb[r1 * VS_STRIDE + c2 * 32 + quad * 8]);

            // ---- fragment 0 (q = qbase..qbase+15) ----
            {
                ffrag Se = {0.f,0.f,0.f,0.f}, So = {0.f,0.f,0.f,0.f};
                Se = __builtin_amdgcn_mfma_f32_16x16x32_bf16(Kfe, Qf0, Se, 0, 0, 0);
                So = __builtin_amdgcn_mfma_f32_16x16x32_bf16(Kfo, Qf0, So, 0, 0, 0);
                union { bfrag f; unsigned int u[4]; } P;
                P.u[0] = pack2h(__builtin_amdgcn_exp2f(Se[0]), __builtin_amdgcn_exp2f(Se[1]));
                P.u[1] = pack2h(__builtin_amdgcn_exp2f(Se[2]), __builtin_amdgcn_exp2f(Se[3]));
                P.u[2] = pack2h(__builtin_amdgcn_exp2f(So[0]), __builtin_amdgcn_exp2f(So[1]));
                P.u[3] = pack2h(__builtin_amdgcn_exp2f(So[2]), __builtin_amdgcn_exp2f(So[3]));
                O00 = __builtin_amdgcn_mfma_f32_16x16x32_bf16(Va0, P.f, O00, 0, 0, 0);
                O01 = __builtin_amdgcn_mfma_f32_16x16x32_bf16(Va1, P.f, O01, 0, 0, 0);
            }
            // ---- fragment 1 (q = qbase+16..qbase+31) ----
            {
                ffrag Se = {0.f,0.f,0.f,0.f}, So = {0.f,0.f,0.f,0.f};
                Se = __builtin_amdgcn_mfma_f32_16x16x32_bf16(Kfe, Qf1, Se, 0, 0, 0);
                So = __builtin_amdgcn_mfma_f32_16x16x32_bf16(Kfo, Qf1, So, 0, 0, 0);
                union { bfrag f; unsigned int u[4]; } P;
                P.u[0] = pack2h(__builtin_amdgcn_exp2f(Se[0]), __builtin_amdgcn_exp2f(Se[1]));
                P.u[1] = pack2h(__builtin_amdgcn_exp2f(Se[2]), __builtin_amdgcn_exp2f(Se[3]));
                P.u[2] = pack2h(__builtin_amdgcn_exp2f(So[0]), __builtin_amdgcn_exp2f(So[1]));
                P.u[3] = pack2h(__builtin_amdgcn_exp2f(So[2]), __builtin_amdgcn_exp2f(So[3]));
                O10 = __builtin_amdgcn_mfma_f32_16x16x32_bf16(Va0, P.f, O10, 0, 0, 0);
                O11 = __builtin_amdgcn_mfma_f32_16x16x32_bf16(Va1, P.f, O11, 0, 0, 0);
            }
        }
    };

    // prologue: stage tile 0 into buffer 0
    {
        const uint4 k4 = *(const uint4*)(Kbase + (size_t)skey * 32 + sch * 8);
        *(uint4*)(&Ks[srow * KS_STRIDE + sch * 8]) = k4;
        if (tid < 400) {
            const uint4 v4 = *(const uint4*)(Vbase + (size_t)sd * 4096 + svch * 8);
            *(uint4*)(&Vs[sd * VS_STRIDE + svch * 8]) = v4;
        }
    }
    __syncthreads();

    int cur = 0;
    for (int t = 0; t < NT - 1; ++t) {
        // issue next tile's loads EARLY (latency hides under compute)
        const int kb = (t + 1) * TK;
        const uint4 k4 = *(const uint4*)(Kbase + (size_t)(kb + skey) * 32 + sch * 8);
        uint4 v4;
        if (tid < 400)
            v4 = *(const uint4*)(Vbase + (size_t)sd * 4096 + kb + svch * 8);
        __builtin_amdgcn_sched_barrier(0);   // pin loads above compute

        compute_tile(Ks + cur * (TK * KS_STRIDE), Vs + cur * (25 * VS_STRIDE));

        // write-late into the other buffer (vmcnt wait auto-inserted here)
        const int nxt = cur ^ 1;
        *(uint4*)(&Ks[nxt * (TK * KS_STRIDE) + srow * KS_STRIDE + sch * 8]) = k4;
        if (tid < 400)
            *(uint4*)(&Vs[nxt * (25 * VS_STRIDE) + sd * VS_STRIDE + svch * 8]) = v4;
        __syncthreads();
        cur = nxt;
    }
    compute_tile(Ks + cur * (TK * KS_STRIDE), Vs + cur * (25 * VS_STRIDE));

    // store fp16 partials: O^T -> Opart[q][d]; l from O*1 d=24 (quad 2, r=0)
    {
        const size_t base0 = ((size_t)split * N_ + qbase + col) * 32;
        uint2 s0;
        s0.x = packh16(O00[0], O00[1]);
        s0.y = packh16(O00[2], O00[3]);
        *(uint2*)(Opart + base0 + quad * 4) = s0;
        if (quad < 2) {
            uint2 s1;
            s1.x = packh16(O01[0], O01[1]);
            s1.y = packh16(O01[2], O01[3]);
            *(uint2*)(Opart + base0 + 16 + quad * 4) = s1;   // d 16..23
        }
        if (quad == 2)
            lpart[(size_t)split * N_ + qbase + col] = O01[0]; // d=24 = l

        const size_t base1 = base0 + 16 * 32;
        uint2 t0;
        t0.x = packh16(O10[0], O10[1]);
        t0.y = packh16(O10[2], O10[3]);
        *(uint2*)(Opart + base1 + quad * 4) = t0;
        if (quad < 2) {
            uint2 t1;
            t1.x = packh16(O11[0], O11[1]);
            t1.y = packh16(O11[2], O11[3]);
            *(uint2*)(Opart + base1 + 16 + quad * 4) = t1;
        }
        if (quad == 2)
            lpart[(size_t)split * N_ + qbase + 16 + col] = O11[0];
    }
}

// ---------------- Kernel 3: combine + output projection ----------------
__global__ __launch_bounds__(256) void combine_kernel(
    const __half* __restrict__ Opart, const float* __restrict__ lpart,
    const unsigned short* __restrict__ wOf, const float* __restrict__ bO,
    float* __restrict__ out)
{
    __shared__ unsigned short Hs[64 * HS_STRIDE];

    const int tid = threadIdx.x;
    const int qb  = blockIdx.x * 64;
    {
        const int ql = tid >> 2;
        const int c8 = (tid & 3) * 8;     // dim chunk 0,8,16,24
        const int q  = qb + ql;
        float a[8] = {0.f, 0.f, 0.f, 0.f, 0.f, 0.f, 0.f, 0.f};
        if (c8 < 24) {                    // chunk 24..31 never written -> zeros
            #pragma unroll
            for (int s = 0; s < NSP; ++s) {
                const __half2* p2 = (const __half2*)(Opart + ((size_t)s * N_ + q) * 32 + c8);
                #pragma unroll
                for (int j = 0; j < 4; ++j) {
                    const float2 f = __half22float2(p2[j]);
                    a[2 * j]     += f.x;
                    a[2 * j + 1] += f.y;
                }
            }
        }
        float ls = 0.f;
        #pragma unroll
        for (int s = 0; s < NSP; ++s) ls += lpart[(size_t)s * N_ + q];
        const float inv = 1.0f / ls;
        uint4 pk;
        pk.x = pack2h(a[0] * inv, a[1] * inv);
        pk.y = pack2h(a[2] * inv, a[3] * inv);
        pk.z = pack2h(a[4] * inv, a[5] * inv);
        pk.w = pack2h(a[6] * inv, a[7] * inv);
        *(uint4*)(&Hs[ql * HS_STRIDE + c8]) = pk;
    }
    __syncthreads();

    const int lane = tid & 63;
    const int w    = tid >> 6;
    const int col  = lane & 15;
    const int quad = lane >> 4;
    const bfrag Hf = *(const bfrag*)(&Hs[(w * 16 + col) * HS_STRIDE + quad * 8]);
    #pragma unroll
    for (int nt = 0; nt < 8; ++nt) {
        const bfrag Wo = *(const bfrag*)(wOf + (nt * 64 + lane) * 8);
        ffrag C = {0.f, 0.f, 0.f, 0.f};
        C = __builtin_amdgcn_mfma_f32_16x16x32_bf16(Hf, Wo, C, 0, 0, 0);
        const float bo = bO[nt * 16 + col];
        #pragma unroll
        for (int r = 0; r < 4; ++r)
            out[(size_t)(qb + w * 16 + quad * 4 + r) * 128 + nt * 16 + col] = C[r] + bo;
    }
}

extern "C" void kernel_launch(void* const* d_in, const int* in_sizes, int n_in,
                              void* d_out, int out_size, void* d_ws, size_t ws_size,
                              hipStream_t stream) {
    const float* x  = (const float*)d_in[0];
    const float* wQ = (const float*)d_in[1];
    const float* bQ = (const float*)d_in[2];
    const float* wK = (const float*)d_in[3];
    const float* bK = (const float*)d_in[4];
    const float* wV = (const float*)d_in[5];
    const float* bV = (const float*)d_in[6];
    const float* wO = (const float*)d_in[7];
    const float* bO = (const float*)d_in[8];
    float* out = (float*)d_out;

    unsigned short* ws16 = (unsigned short*)d_ws;
    unsigned short* Qbf = ws16;                                    // N*32 shorts
    unsigned short* Kbf = Qbf + (size_t)N_ * 32;                   // N*32
    unsigned short* Vt  = Kbf + (size_t)N_ * 32;                   // B*32*S
    unsigned short* Wf  = Vt + (size_t)B_ * 32 * S_;               // 10240
    unsigned short* wOf = Wf + 4 * 5 * 512;                        // 4096
    float* bqkv = (float*)(wOf + 8 * 512);                         // 80 fp32
    __half* Opart = (__half*)(bqkv + 80);                          // NSP*N*32 fp16
    float* lpart = (float*)(Opart + (size_t)NSP * N_ * 32);        // NSP*N fp32

    prep_kernel<<<8, 256, 0, stream>>>(wQ, bQ, wK, bK, wV, bV, wO, Wf, wOf, bqkv);
    proj_kernel<<<N_ / 64, 256, 0, stream>>>(x, Wf, bqkv, Qbf, Kbf, Vt);
    attn_kernel<<<dim3(N_ / 256, NSP), 512, 0, stream>>>(Qbf, Kbf, Vt, Opart, lpart);
    combine_kernel<<<N_ / 64, 256, 0, stream>>>(Opart, lpart, wOf, bO, out);
}